// Round 1
// baseline (535.005 us; speedup 1.0000x reference)
//
#include <hip/hip_runtime.h>

#define NN 50000
#define NE 800000
#define D 128

// ---------------- CSR build ----------------

__global__ void k_degree(const int* __restrict__ dst, int* __restrict__ cnt) {
    int e = blockIdx.x * 256 + threadIdx.x;
    if (e < NE) atomicAdd(&cnt[dst[e]], 1);
}

__global__ void k_dinv(const int* __restrict__ cnt, float* __restrict__ dinv) {
    int i = blockIdx.x * 256 + threadIdx.x;
    if (i < NN) dinv[i] = rsqrtf((float)(cnt[i] + 1));  // +1 self loop
}

__global__ void k_scan_block(const int* __restrict__ cnt, int* __restrict__ excl,
                             int* __restrict__ bsum) {
    __shared__ int sm[256];
    int t = threadIdx.x;
    int idx = blockIdx.x * 256 + t;
    int v = (idx < NN) ? cnt[idx] : 0;
    sm[t] = v;
    __syncthreads();
    for (int o = 1; o < 256; o <<= 1) {
        int u = (t >= o) ? sm[t - o] : 0;
        __syncthreads();
        sm[t] += u;
        __syncthreads();
    }
    if (idx < NN) excl[idx] = sm[t] - v;      // exclusive within block
    if (t == 255) bsum[blockIdx.x] = sm[255]; // block total
}

__global__ void k_scan_top(const int* __restrict__ bsum, int* __restrict__ boff) {
    __shared__ int sm[256];
    const int NB = (NN + 255) / 256; // 196
    int t = threadIdx.x;
    int v = (t < NB) ? bsum[t] : 0;
    sm[t] = v;
    __syncthreads();
    for (int o = 1; o < 256; o <<= 1) {
        int u = (t >= o) ? sm[t - o] : 0;
        __syncthreads();
        sm[t] += u;
        __syncthreads();
    }
    if (t < NB) boff[t] = sm[t] - v;
}

__global__ void k_scan_add(int* __restrict__ rowptr, const int* __restrict__ boff) {
    int idx = blockIdx.x * 256 + threadIdx.x;
    if (idx < NN) rowptr[idx] += boff[idx >> 8];
    else if (idx == NN) rowptr[NN] = NE;
}

__global__ void k_fill(const int* __restrict__ src, const int* __restrict__ dst,
                       const int* __restrict__ rowptr, int* __restrict__ fill,
                       int* __restrict__ col) {
    int e = blockIdx.x * 256 + threadIdx.x;
    if (e < NE) {
        int d = dst[e];
        int pos = rowptr[d] + atomicAdd(&fill[d], 1);
        col[pos] = src[e];
    }
}

// ---------------- GEMM: C[N,D] = H[N,D] @ W[D,D], fp32 ----------------
// 32-row tile per block, H tile staged once (16KB), W staged in 32-k chunks
// (16KB). 256 threads, each computes 4 rows x 4 cols (float4 acc).

__global__ __launch_bounds__(256) void k_gemm(const float* __restrict__ H,
                                              const float* __restrict__ W,
                                              float* __restrict__ C) {
    __shared__ __align__(16) float Hs[32 * D];
    __shared__ __align__(16) float Ws[32 * D];
    int t = threadIdx.x;
    int row0 = blockIdx.x * 32;

    // stage H tile (covers full k range): 32*128 floats = 1024 float4
    #pragma unroll
    for (int i = 0; i < 4; i++) {
        int fl = i * 256 + t;
        int r = fl >> 5;
        int c = (fl & 31) << 2;
        int gr = row0 + r;
        float4 v = make_float4(0.f, 0.f, 0.f, 0.f);
        if (gr < NN) v = *(const float4*)(H + (size_t)gr * D + c);
        *(float4*)(Hs + r * D + c) = v;
    }

    int tc = t & 31, tr = t >> 5;
    int col0 = tc * 4;
    int r0 = tr * 4;
    float4 acc[4];
    #pragma unroll
    for (int m = 0; m < 4; m++) acc[m] = make_float4(0.f, 0.f, 0.f, 0.f);

    for (int kc = 0; kc < D; kc += 32) {
        __syncthreads();
        // stage W chunk: rows kc..kc+31
        #pragma unroll
        for (int i = 0; i < 4; i++) {
            int fl = i * 256 + t;
            int kk = fl >> 5;
            int c = (fl & 31) << 2;
            *(float4*)(Ws + kk * D + c) = *(const float4*)(W + (size_t)(kc + kk) * D + c);
        }
        __syncthreads();
        #pragma unroll
        for (int kk = 0; kk < 32; kk += 4) {
            float4 hv[4], wv[4];
            #pragma unroll
            for (int m = 0; m < 4; m++)
                hv[m] = *(const float4*)(Hs + (r0 + m) * D + kc + kk);
            #pragma unroll
            for (int j = 0; j < 4; j++)
                wv[j] = *(const float4*)(Ws + (kk + j) * D + col0);
            #pragma unroll
            for (int m = 0; m < 4; m++) {
                acc[m].x += hv[m].x * wv[0].x + hv[m].y * wv[1].x + hv[m].z * wv[2].x + hv[m].w * wv[3].x;
                acc[m].y += hv[m].x * wv[0].y + hv[m].y * wv[1].y + hv[m].z * wv[2].y + hv[m].w * wv[3].y;
                acc[m].z += hv[m].x * wv[0].z + hv[m].y * wv[1].z + hv[m].z * wv[2].z + hv[m].w * wv[3].z;
                acc[m].w += hv[m].x * wv[0].w + hv[m].y * wv[1].w + hv[m].z * wv[2].w + hv[m].w * wv[3].w;
            }
        }
    }

    #pragma unroll
    for (int m = 0; m < 4; m++) {
        int gr = row0 + r0 + m;
        if (gr < NN) *(float4*)(C + (size_t)gr * D + col0) = acc[m];
    }
}

// ---------------- Aggregation: out[i] = relu?(dinv[i]*(sum + dinv[i]*t[i]) + b)
// one wave per destination node; lane handles 2 features (float2)

__global__ __launch_bounds__(256) void k_agg(const float* __restrict__ T,
                                             const int* __restrict__ rowptr,
                                             const int* __restrict__ col,
                                             const float* __restrict__ dinv,
                                             const float* __restrict__ bias,
                                             float* __restrict__ out, int relu) {
    int wave = threadIdx.x >> 6;
    int lane = threadIdx.x & 63;
    int i = blockIdx.x * 4 + wave;
    if (i >= NN) return;
    int f = lane * 2;
    float di = dinv[i];
    float2 tv = *(const float2*)(T + (size_t)i * D + f);
    float ax = di * tv.x, ay = di * tv.y;  // self-loop term (pre di scale)
    int r0 = rowptr[i], r1 = rowptr[i + 1];
    for (int e = r0; e < r1; e++) {
        int s = col[e];
        float w = dinv[s];
        float2 sv = *(const float2*)(T + (size_t)s * D + f);
        ax += w * sv.x;
        ay += w * sv.y;
    }
    float bx = bias[f], by = bias[f + 1];
    ax = ax * di + bx;
    ay = ay * di + by;
    if (relu) { ax = fmaxf(ax, 0.f); ay = fmaxf(ay, 0.f); }
    *(float2*)(out + (size_t)i * D + f) = make_float2(ax, ay);
}

// ---------------- launch ----------------

extern "C" void kernel_launch(void* const* d_in, const int* in_sizes, int n_in,
                              void* d_out, int out_size, void* d_ws, size_t ws_size,
                              hipStream_t stream) {
    const float* x  = (const float*)d_in[0];
    const int* edge = (const int*)d_in[1];
    const float* W0 = (const float*)d_in[2];
    const float* b0 = (const float*)d_in[3];
    const float* W1 = (const float*)d_in[4];
    const float* b1 = (const float*)d_in[5];
    const float* W2 = (const float*)d_in[6];
    const float* b2 = (const float*)d_in[7];
    const int* src = edge;        // edge_index[0]
    const int* dst = edge + NE;   // edge_index[1]
    float* out = (float*)d_out;

    char* ws = (char*)d_ws;
    size_t off = 0;
    auto alloc = [&](size_t bytes) {
        void* p = ws + off;
        off += (bytes + 255) & ~(size_t)255;
        return p;
    };
    int*   cnt    = (int*)alloc(NN * 4);
    int*   fill   = (int*)alloc(NN * 4);
    int*   rowptr = (int*)alloc((NN + 1) * 4);
    float* dinv   = (float*)alloc(NN * 4);
    int*   bsum   = (int*)alloc(256 * 4);
    int*   boff   = (int*)alloc(256 * 4);
    int*   col    = (int*)alloc((size_t)NE * 4);
    float* bufA   = (float*)alloc((size_t)NN * D * 4);
    float* bufB   = out;  // reuse d_out for the h1/h2 intermediate

    hipMemsetAsync(cnt, 0, NN * 4, stream);
    hipMemsetAsync(fill, 0, NN * 4, stream);

    k_degree<<<(NE + 255) / 256, 256, 0, stream>>>(dst, cnt);
    k_dinv<<<(NN + 255) / 256, 256, 0, stream>>>(cnt, dinv);
    k_scan_block<<<(NN + 255) / 256, 256, 0, stream>>>(cnt, rowptr, bsum);
    k_scan_top<<<1, 256, 0, stream>>>(bsum, boff);
    k_scan_add<<<(NN + 256) / 256, 256, 0, stream>>>(rowptr, boff);
    k_fill<<<(NE + 255) / 256, 256, 0, stream>>>(src, dst, rowptr, fill, col);

    const int ggrid = (NN + 31) / 32;
    const int agrid = (NN + 3) / 4;

    // layer 0: t = x@W0 ; h1 = relu(agg(t) + b0)
    k_gemm<<<ggrid, 256, 0, stream>>>(x, W0, bufA);
    k_agg<<<agrid, 256, 0, stream>>>(bufA, rowptr, col, dinv, b0, bufB, 1);
    // layer 1
    k_gemm<<<ggrid, 256, 0, stream>>>(bufB, W1, bufA);
    k_agg<<<agrid, 256, 0, stream>>>(bufA, rowptr, col, dinv, b1, bufB, 1);
    // layer 2 (no relu)
    k_gemm<<<ggrid, 256, 0, stream>>>(bufB, W2, bufA);
    k_agg<<<agrid, 256, 0, stream>>>(bufA, rowptr, col, dinv, b2, out, 0);
}

// Round 2
// 451.898 us; speedup vs baseline: 1.1839x; 1.1839x over previous
//
#include <hip/hip_runtime.h>

#define NN 50000
#define NE 800000
#define D 128

// ---------------- CSR build ----------------

__global__ void k_degree(const int* __restrict__ dst, int* __restrict__ cnt) {
    int e = blockIdx.x * 256 + threadIdx.x;
    if (e < NE) atomicAdd(&cnt[dst[e]], 1);
}

__global__ void k_dinv(const int* __restrict__ cnt, float* __restrict__ dinv) {
    int i = blockIdx.x * 256 + threadIdx.x;
    if (i < NN) dinv[i] = rsqrtf((float)(cnt[i] + 1));  // +1 self loop
}

__global__ void k_scan_block(const int* __restrict__ cnt, int* __restrict__ excl,
                             int* __restrict__ bsum) {
    __shared__ int sm[256];
    int t = threadIdx.x;
    int idx = blockIdx.x * 256 + t;
    int v = (idx < NN) ? cnt[idx] : 0;
    sm[t] = v;
    __syncthreads();
    for (int o = 1; o < 256; o <<= 1) {
        int u = (t >= o) ? sm[t - o] : 0;
        __syncthreads();
        sm[t] += u;
        __syncthreads();
    }
    if (idx < NN) excl[idx] = sm[t] - v;
    if (t == 255) bsum[blockIdx.x] = sm[255];
}

__global__ void k_scan_top(const int* __restrict__ bsum, int* __restrict__ boff) {
    __shared__ int sm[256];
    const int NB = (NN + 255) / 256;
    int t = threadIdx.x;
    int v = (t < NB) ? bsum[t] : 0;
    sm[t] = v;
    __syncthreads();
    for (int o = 1; o < 256; o <<= 1) {
        int u = (t >= o) ? sm[t - o] : 0;
        __syncthreads();
        sm[t] += u;
        __syncthreads();
    }
    if (t < NB) boff[t] = sm[t] - v;
}

__global__ void k_scan_add(int* __restrict__ rowptr, const int* __restrict__ boff) {
    int idx = blockIdx.x * 256 + threadIdx.x;
    if (idx < NN) rowptr[idx] += boff[idx >> 8];
    else if (idx == NN) rowptr[NN] = NE;
}

__global__ void k_fill(const int* __restrict__ src, const int* __restrict__ dst,
                       const int* __restrict__ rowptr, int* __restrict__ fill,
                       int* __restrict__ col) {
    int e = blockIdx.x * 256 + threadIdx.x;
    if (e < NE) {
        int d = dst[e];
        int pos = rowptr[d] + atomicAdd(&fill[d], 1);
        col[pos] = src[e];
    }
}

// ---------------- GEMM: C[r] = dinv[r] * (H[r] @ W), fp32 ----------------
// 64-row x 128-col tile, 256 threads, 8x4 outputs/thread. LDS reads are
// broadcast-friendly (32 lanes share each H address; W reads contiguous).
// Epilogue scales each row by dinv[row] so agg never gathers dinv[src].

__global__ __launch_bounds__(256) void k_gemm(const float* __restrict__ H,
                                              const float* __restrict__ W,
                                              const float* __restrict__ dinv,
                                              float* __restrict__ C) {
    __shared__ __align__(16) float Hs[64 * 32];   // [row][k]  8 KB
    __shared__ __align__(16) float Ws[32 * 128];  // [k][col] 16 KB
    int t = threadIdx.x;
    int row0 = blockIdx.x * 64;
    int tx = t & 31, ty = t >> 5;   // tx: col group (4 cols), ty: row group (8 rows)

    float4 acc[8];
    #pragma unroll
    for (int m = 0; m < 8; m++) acc[m] = make_float4(0.f, 0.f, 0.f, 0.f);

    for (int kc = 0; kc < D; kc += 32) {
        __syncthreads();
        // stage Hs: 64 rows x 32 k = 512 float4
        #pragma unroll
        for (int i = 0; i < 2; i++) {
            int fl = i * 256 + t;
            int r = fl >> 3, c4 = (fl & 7) << 2;
            int gr = row0 + r;
            float4 v = make_float4(0.f, 0.f, 0.f, 0.f);
            if (gr < NN) v = *(const float4*)(H + (size_t)gr * D + kc + c4);
            *(float4*)(Hs + r * 32 + c4) = v;
        }
        // stage Ws: 32 k x 128 col = 1024 float4
        #pragma unroll
        for (int i = 0; i < 4; i++) {
            int fl = i * 256 + t;
            int kk = fl >> 5, c4 = (fl & 31) << 2;
            *(float4*)(Ws + kk * D + c4) = *(const float4*)(W + (size_t)(kc + kk) * D + c4);
        }
        __syncthreads();
        #pragma unroll
        for (int kk = 0; kk < 32; kk += 4) {
            float4 wf[4], hf[8];
            #pragma unroll
            for (int j = 0; j < 4; j++)
                wf[j] = *(const float4*)(Ws + (kk + j) * D + tx * 4);
            #pragma unroll
            for (int m = 0; m < 8; m++)
                hf[m] = *(const float4*)(Hs + (ty * 8 + m) * 32 + kk);
            #pragma unroll
            for (int m = 0; m < 8; m++) {
                acc[m].x += hf[m].x * wf[0].x + hf[m].y * wf[1].x + hf[m].z * wf[2].x + hf[m].w * wf[3].x;
                acc[m].y += hf[m].x * wf[0].y + hf[m].y * wf[1].y + hf[m].z * wf[2].y + hf[m].w * wf[3].y;
                acc[m].z += hf[m].x * wf[0].z + hf[m].y * wf[1].z + hf[m].z * wf[2].z + hf[m].w * wf[3].z;
                acc[m].w += hf[m].x * wf[0].w + hf[m].y * wf[1].w + hf[m].z * wf[2].w + hf[m].w * wf[3].w;
            }
        }
    }
    #pragma unroll
    for (int m = 0; m < 8; m++) {
        int gr = row0 + ty * 8 + m;
        if (gr < NN) {
            float s = dinv[gr];
            float4 v = make_float4(acc[m].x * s, acc[m].y * s, acc[m].z * s, acc[m].w * s);
            *(float4*)(C + (size_t)gr * D + tx * 4) = v;
        }
    }
}

// ---------------- Aggregation ----------------
// T is pre-scaled by dinv[row]: out[i] = dinv[i]*(sum_s T[s] + T[i]) + b.
// One wave per node, lane = 2 features. Edge loop unrolled x4 so four
// independent row loads are in flight (break the latency chain).

__global__ __launch_bounds__(256) void k_agg(const float* __restrict__ T,
                                             const int* __restrict__ rowptr,
                                             const int* __restrict__ col,
                                             const float* __restrict__ dinv,
                                             const float* __restrict__ bias,
                                             float* __restrict__ out, int relu) {
    int wave = threadIdx.x >> 6;
    int lane = threadIdx.x & 63;
    int i = blockIdx.x * 4 + wave;
    if (i >= NN) return;
    int f = lane * 2;
    float di = dinv[i];
    float2 tv = *(const float2*)(T + (size_t)i * D + f);  // T'[i] = di*t[i]
    float ax = tv.x, ay = tv.y;
    int e = rowptr[i], r1 = rowptr[i + 1];
    for (; e + 4 <= r1; e += 4) {
        int s0 = col[e], s1 = col[e + 1], s2 = col[e + 2], s3 = col[e + 3];
        float2 v0 = *(const float2*)(T + (size_t)s0 * D + f);
        float2 v1 = *(const float2*)(T + (size_t)s1 * D + f);
        float2 v2 = *(const float2*)(T + (size_t)s2 * D + f);
        float2 v3 = *(const float2*)(T + (size_t)s3 * D + f);
        ax += (v0.x + v1.x) + (v2.x + v3.x);
        ay += (v0.y + v1.y) + (v2.y + v3.y);
    }
    for (; e < r1; e++) {
        int s = col[e];
        float2 sv = *(const float2*)(T + (size_t)s * D + f);
        ax += sv.x;
        ay += sv.y;
    }
    float bx = bias[f], by = bias[f + 1];
    ax = ax * di + bx;
    ay = ay * di + by;
    if (relu) { ax = fmaxf(ax, 0.f); ay = fmaxf(ay, 0.f); }
    *(float2*)(out + (size_t)i * D + f) = make_float2(ax, ay);
}

// ---------------- launch ----------------

extern "C" void kernel_launch(void* const* d_in, const int* in_sizes, int n_in,
                              void* d_out, int out_size, void* d_ws, size_t ws_size,
                              hipStream_t stream) {
    const float* x  = (const float*)d_in[0];
    const int* edge = (const int*)d_in[1];
    const float* W0 = (const float*)d_in[2];
    const float* b0 = (const float*)d_in[3];
    const float* W1 = (const float*)d_in[4];
    const float* b1 = (const float*)d_in[5];
    const float* W2 = (const float*)d_in[6];
    const float* b2 = (const float*)d_in[7];
    const int* src = edge;
    const int* dst = edge + NE;
    float* out = (float*)d_out;

    char* ws = (char*)d_ws;
    size_t off = 0;
    auto alloc = [&](size_t bytes) {
        void* p = ws + off;
        off += (bytes + 255) & ~(size_t)255;
        return p;
    };
    int*   cnt    = (int*)alloc(NN * 4);
    int*   fill   = (int*)alloc(NN * 4);
    int*   rowptr = (int*)alloc((NN + 1) * 4);
    float* dinv   = (float*)alloc(NN * 4);
    int*   bsum   = (int*)alloc(256 * 4);
    int*   boff   = (int*)alloc(256 * 4);
    int*   col    = (int*)alloc((size_t)NE * 4);
    float* bufA   = (float*)alloc((size_t)NN * D * 4);
    float* bufB   = out;  // reuse d_out for h1/h2

    hipMemsetAsync(cnt, 0, NN * 4, stream);
    hipMemsetAsync(fill, 0, NN * 4, stream);

    k_degree<<<(NE + 255) / 256, 256, 0, stream>>>(dst, cnt);
    k_dinv<<<(NN + 255) / 256, 256, 0, stream>>>(cnt, dinv);
    k_scan_block<<<(NN + 255) / 256, 256, 0, stream>>>(cnt, rowptr, bsum);
    k_scan_top<<<1, 256, 0, stream>>>(bsum, boff);
    k_scan_add<<<(NN + 256) / 256, 256, 0, stream>>>(rowptr, boff);
    k_fill<<<(NE + 255) / 256, 256, 0, stream>>>(src, dst, rowptr, fill, col);

    const int ggrid = (NN + 63) / 64;
    const int agrid = (NN + 3) / 4;

    // layer 0: T' = dinv * (x@W0); h1 = relu(dinv*(agg T') + b0)
    k_gemm<<<ggrid, 256, 0, stream>>>(x, W0, dinv, bufA);
    k_agg<<<agrid, 256, 0, stream>>>(bufA, rowptr, col, dinv, b0, bufB, 1);
    // layer 1
    k_gemm<<<ggrid, 256, 0, stream>>>(bufB, W1, dinv, bufA);
    k_agg<<<agrid, 256, 0, stream>>>(bufA, rowptr, col, dinv, b1, bufB, 1);
    // layer 2 (no relu)
    k_gemm<<<ggrid, 256, 0, stream>>>(bufB, W2, dinv, bufA);
    k_agg<<<agrid, 256, 0, stream>>>(bufA, rowptr, col, dinv, b2, out, 0);
}

// Round 3
// 344.600 us; speedup vs baseline: 1.5525x; 1.3114x over previous
//
#include <hip/hip_runtime.h>

#define NN 50000
#define NPAD 50048
#define NE 800000
#define D 128
#define BPAD 136

typedef __attribute__((ext_vector_type(8))) short bf16x8;
typedef __attribute__((ext_vector_type(4))) float f32x4;

__device__ inline unsigned short f2bf(float f) {
    unsigned int b = __float_as_uint(f);
    return (unsigned short)((b + 0x7FFFu + ((b >> 16) & 1u)) >> 16);
}
__device__ inline float bf2f(unsigned short u) {
    return __uint_as_float(((unsigned int)u) << 16);
}

// ---------------- CSR build ----------------

__global__ void k_degree(const int* __restrict__ dst, int* __restrict__ cnt) {
    int e = blockIdx.x * 256 + threadIdx.x;
    if (e < NE) atomicAdd(&cnt[dst[e]], 1);
}

__global__ void k_dinv(const int* __restrict__ cnt, float* __restrict__ dinv) {
    int i = blockIdx.x * 256 + threadIdx.x;
    if (i < NN) dinv[i] = rsqrtf((float)(cnt[i] + 1));
}

__global__ void k_scan_block(const int* __restrict__ cnt, int* __restrict__ excl,
                             int* __restrict__ bsum) {
    __shared__ int sm[256];
    int t = threadIdx.x;
    int idx = blockIdx.x * 256 + t;
    int v = (idx < NN) ? cnt[idx] : 0;
    sm[t] = v;
    __syncthreads();
    for (int o = 1; o < 256; o <<= 1) {
        int u = (t >= o) ? sm[t - o] : 0;
        __syncthreads();
        sm[t] += u;
        __syncthreads();
    }
    if (idx < NN) excl[idx] = sm[t] - v;
    if (t == 255) bsum[blockIdx.x] = sm[255];
}

__global__ void k_scan_top(const int* __restrict__ bsum, int* __restrict__ boff) {
    __shared__ int sm[256];
    const int NB = (NN + 255) / 256;
    int t = threadIdx.x;
    int v = (t < NB) ? bsum[t] : 0;
    sm[t] = v;
    __syncthreads();
    for (int o = 1; o < 256; o <<= 1) {
        int u = (t >= o) ? sm[t - o] : 0;
        __syncthreads();
        sm[t] += u;
        __syncthreads();
    }
    if (t < NB) boff[t] = sm[t] - v;
}

__global__ void k_scan_add(int* __restrict__ rowptr, const int* __restrict__ boff) {
    int idx = blockIdx.x * 256 + threadIdx.x;
    if (idx < NN) rowptr[idx] += boff[idx >> 8];
    else if (idx == NN) rowptr[NN] = NE;
}

__global__ void k_fill(const int* __restrict__ src, const int* __restrict__ dst,
                       const int* __restrict__ rowptr, int* __restrict__ fill,
                       int* __restrict__ col) {
    int e = blockIdx.x * 256 + threadIdx.x;
    if (e < NE) {
        int d = dst[e];
        int pos = rowptr[d] + atomicAdd(&fill[d], 1);
        col[pos] = src[e];
    }
}

// ---------------- prep: split-bf16 conversions ----------------

// x[N,D] fp32 -> Xh, Xl bf16
__global__ void k_convX(const float* __restrict__ X, unsigned short* __restrict__ Xh,
                        unsigned short* __restrict__ Xl) {
    int i4 = blockIdx.x * 256 + threadIdx.x;
    if (i4 >= NN * D / 4) return;
    float4 v = *(const float4*)(X + (size_t)i4 * 4);
    ushort4 h, l;
    h.x = f2bf(v.x); l.x = f2bf(v.x - bf2f(h.x));
    h.y = f2bf(v.y); l.y = f2bf(v.y - bf2f(h.y));
    h.z = f2bf(v.z); l.z = f2bf(v.z - bf2f(h.z));
    h.w = f2bf(v.w); l.w = f2bf(v.w - bf2f(h.w));
    *(ushort4*)(Xh + (size_t)i4 * 4) = h;
    *(ushort4*)(Xl + (size_t)i4 * 4) = l;
}

// W[D,D] fp32 -> WhT, WlT bf16 transposed ([col][k])
__global__ void k_convW(const float* __restrict__ W, unsigned short* __restrict__ WhT,
                        unsigned short* __restrict__ WlT) {
    int i = blockIdx.x * 256 + threadIdx.x;
    if (i >= D * D) return;
    int k = i >> 7, c = i & 127;
    float v = W[i];
    unsigned short h = f2bf(v);
    unsigned short l = f2bf(v - bf2f(h));
    WhT[c * D + k] = h;
    WlT[c * D + k] = l;
}

// ---------------- GEMM: C[r] = dinv[r] * (A[r] @ W), split-bf16 MFMA ------
// Block: 128 rows x 128 cols, 4 waves (2x2), wave = 64x64.
// B (=W^T, both halves) staged once in LDS; A fragments load from global.
// 3 products: Ah*Bh + Al*Bh + Ah*Bl. No barriers in the k loop.

__global__ __launch_bounds__(256) void k_gemm_mfma(
        const unsigned short* __restrict__ Ah, const unsigned short* __restrict__ Al,
        const unsigned short* __restrict__ BhT, const unsigned short* __restrict__ BlT,
        const float* __restrict__ dinv, float* __restrict__ C) {
    __shared__ short Bs_h[D * BPAD];
    __shared__ short Bs_l[D * BPAD];
    int t = threadIdx.x;

    // stage both W^T halves: thread -> col = t>>1, k-half = (t&1)*64
    {
        int c = t >> 1;
        int k0 = (t & 1) * 64;
        const unsigned short* gh = BhT + c * D + k0;
        const unsigned short* gl = BlT + c * D + k0;
        short* dh = Bs_h + c * BPAD + k0;
        short* dl = Bs_l + c * BPAD + k0;
        #pragma unroll
        for (int i = 0; i < 8; i++)
            *(int4*)(dh + i * 8) = *(const int4*)(gh + i * 8);
        #pragma unroll
        for (int i = 0; i < 8; i++)
            *(int4*)(dl + i * 8) = *(const int4*)(gl + i * 8);
    }
    __syncthreads();

    int w = t >> 6, ln = t & 63;
    int wr = w >> 1, wc = w & 1;
    int R0 = blockIdx.x * 128 + wr * 64;
    int C0 = wc * 64;
    int lr = ln & 15, lg = ln >> 4;

    f32x4 acc[4][4];
    #pragma unroll
    for (int a = 0; a < 4; a++)
        #pragma unroll
        for (int b = 0; b < 4; b++)
            acc[a][b] = (f32x4){0.f, 0.f, 0.f, 0.f};

    const unsigned short* Abh = Ah + (size_t)(R0 + lr) * D + lg * 8;
    const unsigned short* Abl = Al + (size_t)(R0 + lr) * D + lg * 8;

    #pragma unroll
    for (int ks = 0; ks < 4; ks++) {
        int ko = ks * 32;
        bf16x8 fa_h[4], fa_l[4], fb_h[4], fb_l[4];
        #pragma unroll
        for (int fr = 0; fr < 4; fr++) {
            fa_h[fr] = *(const bf16x8*)(Abh + fr * 16 * D + ko);
            fa_l[fr] = *(const bf16x8*)(Abl + fr * 16 * D + ko);
        }
        #pragma unroll
        for (int fc = 0; fc < 4; fc++) {
            int cidx = (C0 + fc * 16 + lr) * BPAD + ko + lg * 8;
            fb_h[fc] = *(const bf16x8*)(Bs_h + cidx);
            fb_l[fc] = *(const bf16x8*)(Bs_l + cidx);
        }
        #pragma unroll
        for (int fr = 0; fr < 4; fr++) {
            #pragma unroll
            for (int fc = 0; fc < 4; fc++) {
                acc[fr][fc] = __builtin_amdgcn_mfma_f32_16x16x32_bf16(
                    fa_h[fr], fb_h[fc], acc[fr][fc], 0, 0, 0);
                acc[fr][fc] = __builtin_amdgcn_mfma_f32_16x16x32_bf16(
                    fa_l[fr], fb_h[fc], acc[fr][fc], 0, 0, 0);
                acc[fr][fc] = __builtin_amdgcn_mfma_f32_16x16x32_bf16(
                    fa_h[fr], fb_l[fc], acc[fr][fc], 0, 0, 0);
            }
        }
    }

    // epilogue: scale by dinv[row], store fp32
    #pragma unroll
    for (int fr = 0; fr < 4; fr++) {
        int rb = R0 + fr * 16 + lg * 4;
        #pragma unroll
        for (int j = 0; j < 4; j++) {
            int r = rb + j;
            if (r < NN) {
                float s = dinv[r];
                #pragma unroll
                for (int fc = 0; fc < 4; fc++)
                    C[(size_t)r * D + C0 + fc * 16 + lr] = acc[fr][fc][j] * s;
            }
        }
    }
}

// ---------------- Aggregation ----------------
// T pre-scaled by dinv[row]. out[i] = dinv[i]*(sum_s T[s] + T[i]) + b.
// mode 1: relu, write split bf16 (Oh/Ol). mode 0: no relu, write fp32 Of.

__global__ __launch_bounds__(256) void k_agg(const float* __restrict__ T,
                                             const int* __restrict__ rowptr,
                                             const int* __restrict__ col,
                                             const float* __restrict__ dinv,
                                             const float* __restrict__ bias,
                                             unsigned short* __restrict__ Oh,
                                             unsigned short* __restrict__ Ol,
                                             float* __restrict__ Of, int mode) {
    int wave = threadIdx.x >> 6;
    int lane = threadIdx.x & 63;
    int i = blockIdx.x * 4 + wave;
    if (i >= NN) return;
    int f = lane * 2;
    float di = dinv[i];
    float2 tv = *(const float2*)(T + (size_t)i * D + f);
    float ax = tv.x, ay = tv.y;
    int e = rowptr[i], r1 = rowptr[i + 1];
    for (; e + 4 <= r1; e += 4) {
        int s0 = col[e], s1 = col[e + 1], s2 = col[e + 2], s3 = col[e + 3];
        float2 v0 = *(const float2*)(T + (size_t)s0 * D + f);
        float2 v1 = *(const float2*)(T + (size_t)s1 * D + f);
        float2 v2 = *(const float2*)(T + (size_t)s2 * D + f);
        float2 v3 = *(const float2*)(T + (size_t)s3 * D + f);
        ax += (v0.x + v1.x) + (v2.x + v3.x);
        ay += (v0.y + v1.y) + (v2.y + v3.y);
    }
    for (; e < r1; e++) {
        int s = col[e];
        float2 sv = *(const float2*)(T + (size_t)s * D + f);
        ax += sv.x;
        ay += sv.y;
    }
    ax = ax * di + bias[f];
    ay = ay * di + bias[f + 1];
    if (mode) {
        ax = fmaxf(ax, 0.f);
        ay = fmaxf(ay, 0.f);
        unsigned short hx = f2bf(ax), hy = f2bf(ay);
        unsigned short lx = f2bf(ax - bf2f(hx)), ly = f2bf(ay - bf2f(hy));
        *(unsigned int*)(Oh + (size_t)i * D + f) = (unsigned int)hx | ((unsigned int)hy << 16);
        *(unsigned int*)(Ol + (size_t)i * D + f) = (unsigned int)lx | ((unsigned int)ly << 16);
    } else {
        *(float2*)(Of + (size_t)i * D + f) = make_float2(ax, ay);
    }
}

// ---------------- launch ----------------

extern "C" void kernel_launch(void* const* d_in, const int* in_sizes, int n_in,
                              void* d_out, int out_size, void* d_ws, size_t ws_size,
                              hipStream_t stream) {
    const float* x  = (const float*)d_in[0];
    const int* edge = (const int*)d_in[1];
    const float* W0 = (const float*)d_in[2];
    const float* b0 = (const float*)d_in[3];
    const float* W1 = (const float*)d_in[4];
    const float* b1 = (const float*)d_in[5];
    const float* W2 = (const float*)d_in[6];
    const float* b2 = (const float*)d_in[7];
    const int* src = edge;
    const int* dst = edge + NE;
    float* out = (float*)d_out;

    char* ws = (char*)d_ws;
    size_t off = 0;
    auto alloc = [&](size_t bytes) {
        void* p = ws + off;
        off += (bytes + 255) & ~(size_t)255;
        return p;
    };
    int*   cnt    = (int*)alloc(NN * 4);
    int*   fill   = (int*)alloc(NN * 4);
    int*   rowptr = (int*)alloc((NN + 1) * 4);
    float* dinv   = (float*)alloc(NN * 4);
    int*   bsum   = (int*)alloc(256 * 4);
    int*   boff   = (int*)alloc(256 * 4);
    int*   col    = (int*)alloc((size_t)NE * 4);
    unsigned short* w0h = (unsigned short*)alloc(D * D * 2);
    unsigned short* w0l = (unsigned short*)alloc(D * D * 2);
    unsigned short* w1h = (unsigned short*)alloc(D * D * 2);
    unsigned short* w1l = (unsigned short*)alloc(D * D * 2);
    unsigned short* w2h = (unsigned short*)alloc(D * D * 2);
    unsigned short* w2l = (unsigned short*)alloc(D * D * 2);
    unsigned short* Xh = (unsigned short*)alloc((size_t)NPAD * D * 2);
    unsigned short* Xl = (unsigned short*)alloc((size_t)NPAD * D * 2);
    float* T = (float*)alloc((size_t)NPAD * D * 4);

    hipMemsetAsync(cnt, 0, NN * 4, stream);
    hipMemsetAsync(fill, 0, NN * 4, stream);

    k_degree<<<(NE + 255) / 256, 256, 0, stream>>>(dst, cnt);
    k_dinv<<<(NN + 255) / 256, 256, 0, stream>>>(cnt, dinv);
    k_scan_block<<<(NN + 255) / 256, 256, 0, stream>>>(cnt, rowptr, bsum);
    k_scan_top<<<1, 256, 0, stream>>>(bsum, boff);
    k_scan_add<<<(NN + 256) / 256, 256, 0, stream>>>(rowptr, boff);
    k_fill<<<(NE + 255) / 256, 256, 0, stream>>>(src, dst, rowptr, fill, col);

    k_convW<<<(D * D + 255) / 256, 256, 0, stream>>>(W0, w0h, w0l);
    k_convW<<<(D * D + 255) / 256, 256, 0, stream>>>(W1, w1h, w1l);
    k_convW<<<(D * D + 255) / 256, 256, 0, stream>>>(W2, w2h, w2l);
    k_convX<<<(NN * D / 4 + 255) / 256, 256, 0, stream>>>(x, Xh, Xl);

    const int ggrid = (NN + 127) / 128;
    const int agrid = (NN + 3) / 4;

    // layer 0
    k_gemm_mfma<<<ggrid, 256, 0, stream>>>(Xh, Xl, w0h, w0l, dinv, T);
    k_agg<<<agrid, 256, 0, stream>>>(T, rowptr, col, dinv, b0, Xh, Xl, out, 1);
    // layer 1
    k_gemm_mfma<<<ggrid, 256, 0, stream>>>(Xh, Xl, w1h, w1l, dinv, T);
    k_agg<<<agrid, 256, 0, stream>>>(T, rowptr, col, dinv, b1, Xh, Xl, out, 1);
    // layer 2 (no relu, fp32 out)
    k_gemm_mfma<<<ggrid, 256, 0, stream>>>(Xh, Xl, w2h, w2l, dinv, T);
    k_agg<<<agrid, 256, 0, stream>>>(T, rowptr, col, dinv, b2, Xh, Xl, out, 0);
}

// Round 4
// 282.774 us; speedup vs baseline: 1.8920x; 1.2186x over previous
//
#include <hip/hip_runtime.h>
#include <hip/hip_fp16.h>

#define NN 50000
#define NPAD 50048
#define NE 800000
#define D 128
#define BPAD 136

typedef __attribute__((ext_vector_type(8))) short bf16x8;
typedef __attribute__((ext_vector_type(4))) float f32x4;

__device__ inline unsigned short f2bf(float f) {
    unsigned int b = __float_as_uint(f);
    return (unsigned short)((b + 0x7FFFu + ((b >> 16) & 1u)) >> 16);
}
__device__ inline float bf2f(unsigned short u) {
    return __uint_as_float(((unsigned int)u) << 16);
}

// ---------------- CSR build ----------------

__global__ void k_degree(const int* __restrict__ dst, int* __restrict__ cnt) {
    int e = blockIdx.x * 256 + threadIdx.x;
    if (e < NE) atomicAdd(&cnt[dst[e]], 1);
}

__global__ void k_dinv(const int* __restrict__ cnt, float* __restrict__ dinv) {
    int i = blockIdx.x * 256 + threadIdx.x;
    if (i < NN) dinv[i] = rsqrtf((float)(cnt[i] + 1));
}

__global__ void k_scan_block(const int* __restrict__ cnt, int* __restrict__ excl,
                             int* __restrict__ bsum) {
    __shared__ int sm[256];
    int t = threadIdx.x;
    int idx = blockIdx.x * 256 + t;
    int v = (idx < NN) ? cnt[idx] : 0;
    sm[t] = v;
    __syncthreads();
    for (int o = 1; o < 256; o <<= 1) {
        int u = (t >= o) ? sm[t - o] : 0;
        __syncthreads();
        sm[t] += u;
        __syncthreads();
    }
    if (idx < NN) excl[idx] = sm[t] - v;
    if (t == 255) bsum[blockIdx.x] = sm[255];
}

__global__ void k_scan_top(const int* __restrict__ bsum, int* __restrict__ boff) {
    __shared__ int sm[256];
    const int NB = (NN + 255) / 256;
    int t = threadIdx.x;
    int v = (t < NB) ? bsum[t] : 0;
    sm[t] = v;
    __syncthreads();
    for (int o = 1; o < 256; o <<= 1) {
        int u = (t >= o) ? sm[t - o] : 0;
        __syncthreads();
        sm[t] += u;
        __syncthreads();
    }
    if (t < NB) boff[t] = sm[t] - v;
}

__global__ void k_scan_add(int* __restrict__ rowptr, const int* __restrict__ boff) {
    int idx = blockIdx.x * 256 + threadIdx.x;
    if (idx < NN) rowptr[idx] += boff[idx >> 8];
    else if (idx == NN) rowptr[NN] = NE;
}

__global__ void k_fill(const int* __restrict__ src, const int* __restrict__ dst,
                       const int* __restrict__ rowptr, int* __restrict__ fill,
                       int* __restrict__ col) {
    int e = blockIdx.x * 256 + threadIdx.x;
    if (e < NE) {
        int d = dst[e];
        int pos = rowptr[d] + atomicAdd(&fill[d], 1);
        col[pos] = src[e];
    }
}

// ---------------- prep: split-bf16 conversions ----------------

__global__ void k_convX(const float* __restrict__ X, unsigned short* __restrict__ Xh,
                        unsigned short* __restrict__ Xl) {
    int i4 = blockIdx.x * 256 + threadIdx.x;
    if (i4 >= NN * D / 4) return;
    float4 v = *(const float4*)(X + (size_t)i4 * 4);
    ushort4 h, l;
    h.x = f2bf(v.x); l.x = f2bf(v.x - bf2f(h.x));
    h.y = f2bf(v.y); l.y = f2bf(v.y - bf2f(h.y));
    h.z = f2bf(v.z); l.z = f2bf(v.z - bf2f(h.z));
    h.w = f2bf(v.w); l.w = f2bf(v.w - bf2f(h.w));
    *(ushort4*)(Xh + (size_t)i4 * 4) = h;
    *(ushort4*)(Xl + (size_t)i4 * 4) = l;
}

__global__ void k_convW(const float* __restrict__ W, unsigned short* __restrict__ WhT,
                        unsigned short* __restrict__ WlT) {
    int i = blockIdx.x * 256 + threadIdx.x;
    if (i >= D * D) return;
    int k = i >> 7, c = i & 127;
    float v = W[i];
    unsigned short h = f2bf(v);
    unsigned short l = f2bf(v - bf2f(h));
    WhT[c * D + k] = h;
    WlT[c * D + k] = l;
}

// ---------------- GEMM: C[r] = fp16( dinv[r] * (A[r] @ W) ) ----------------
// Block: 64 rows x 128 cols, 4 waves (2x2), wave = 32x64.
// Bh (W^T high) staged in LDS (34 KB); Bl fragments read from global (W^T is
// 32 KB -> L1/L2 resident). A fragments from global. 3 bf16 products.

__global__ __launch_bounds__(256, 3) void k_gemm_mfma(
        const unsigned short* __restrict__ Ah, const unsigned short* __restrict__ Al,
        const unsigned short* __restrict__ BhT, const unsigned short* __restrict__ BlT,
        const float* __restrict__ dinv, __half* __restrict__ C) {
    __shared__ short Bs_h[D * BPAD];
    int t = threadIdx.x;
    {
        int c = t >> 1;
        int k0 = (t & 1) * 64;
        const unsigned short* gh = BhT + c * D + k0;
        short* dh = Bs_h + c * BPAD + k0;
        #pragma unroll
        for (int i = 0; i < 8; i++)
            *(int4*)(dh + i * 8) = *(const int4*)(gh + i * 8);
    }
    __syncthreads();

    int w = t >> 6, ln = t & 63;
    int wr = w >> 1, wc = w & 1;
    int R0 = blockIdx.x * 64 + wr * 32;
    int C0 = wc * 64;
    int lr = ln & 15, lg = ln >> 4;

    f32x4 acc[2][4];
    #pragma unroll
    for (int a = 0; a < 2; a++)
        #pragma unroll
        for (int b = 0; b < 4; b++)
            acc[a][b] = (f32x4){0.f, 0.f, 0.f, 0.f};

    const unsigned short* Abh = Ah + (size_t)(R0 + lr) * D + lg * 8;
    const unsigned short* Abl = Al + (size_t)(R0 + lr) * D + lg * 8;

    #pragma unroll
    for (int ks = 0; ks < 4; ks++) {
        int ko = ks * 32;
        bf16x8 fa_h[2], fa_l[2], fb_h[4], fb_l[4];
        #pragma unroll
        for (int fr = 0; fr < 2; fr++) {
            fa_h[fr] = *(const bf16x8*)(Abh + fr * 16 * D + ko);
            fa_l[fr] = *(const bf16x8*)(Abl + fr * 16 * D + ko);
        }
        #pragma unroll
        for (int fc = 0; fc < 4; fc++) {
            int ccol = C0 + fc * 16 + lr;
            fb_h[fc] = *(const bf16x8*)(Bs_h + ccol * BPAD + ko + lg * 8);
            fb_l[fc] = *(const bf16x8*)(BlT + (size_t)ccol * D + ko + lg * 8);
        }
        #pragma unroll
        for (int fr = 0; fr < 2; fr++) {
            #pragma unroll
            for (int fc = 0; fc < 4; fc++) {
                acc[fr][fc] = __builtin_amdgcn_mfma_f32_16x16x32_bf16(
                    fa_h[fr], fb_h[fc], acc[fr][fc], 0, 0, 0);
                acc[fr][fc] = __builtin_amdgcn_mfma_f32_16x16x32_bf16(
                    fa_l[fr], fb_h[fc], acc[fr][fc], 0, 0, 0);
                acc[fr][fc] = __builtin_amdgcn_mfma_f32_16x16x32_bf16(
                    fa_h[fr], fb_l[fc], acc[fr][fc], 0, 0, 0);
            }
        }
    }

    #pragma unroll
    for (int fr = 0; fr < 2; fr++) {
        int rb = R0 + fr * 16 + lg * 4;
        #pragma unroll
        for (int j = 0; j < 4; j++) {
            int r = rb + j;
            if (r < NN) {
                float s = dinv[r];
                #pragma unroll
                for (int fc = 0; fc < 4; fc++)
                    C[(size_t)r * D + C0 + fc * 16 + lr] =
                        __float2half_rn(acc[fr][fc][j] * s);
            }
        }
    }
}

// ---------------- Aggregation ----------------
// T fp16, pre-scaled by dinv[row]. out[i] = dinv[i]*(sum_s T[s] + T[i]) + b.
// One wave per node, lane = 2 features (half2 = 4B). Edge loop unrolled x8.

__global__ __launch_bounds__(256) void k_agg(const __half* __restrict__ T,
                                             const int* __restrict__ rowptr,
                                             const int* __restrict__ col,
                                             const float* __restrict__ dinv,
                                             const float* __restrict__ bias,
                                             unsigned short* __restrict__ Oh,
                                             unsigned short* __restrict__ Ol,
                                             float* __restrict__ Of, int mode) {
    int wave = threadIdx.x >> 6;
    int lane = threadIdx.x & 63;
    int i = blockIdx.x * 4 + wave;
    if (i >= NN) return;
    int f = lane * 2;
    float di = dinv[i];
    float2 tv = __half22float2(*(const __half2*)(T + (size_t)i * D + f));
    float ax = tv.x, ay = tv.y;
    int e = rowptr[i], r1 = rowptr[i + 1];
    for (; e + 8 <= r1; e += 8) {
        float2 v[8];
        #pragma unroll
        for (int u = 0; u < 8; u++) {
            int s = col[e + u];
            v[u] = __half22float2(*(const __half2*)(T + (size_t)s * D + f));
        }
        #pragma unroll
        for (int u = 0; u < 8; u++) { ax += v[u].x; ay += v[u].y; }
    }
    for (; e + 4 <= r1; e += 4) {
        float2 v[4];
        #pragma unroll
        for (int u = 0; u < 4; u++) {
            int s = col[e + u];
            v[u] = __half22float2(*(const __half2*)(T + (size_t)s * D + f));
        }
        #pragma unroll
        for (int u = 0; u < 4; u++) { ax += v[u].x; ay += v[u].y; }
    }
    for (; e < r1; e++) {
        int s = col[e];
        float2 sv = __half22float2(*(const __half2*)(T + (size_t)s * D + f));
        ax += sv.x;
        ay += sv.y;
    }
    float2 bv = *(const float2*)(bias + f);
    ax = ax * di + bv.x;
    ay = ay * di + bv.y;
    if (mode) {
        ax = fmaxf(ax, 0.f);
        ay = fmaxf(ay, 0.f);
        unsigned short hx = f2bf(ax), hy = f2bf(ay);
        unsigned short lx = f2bf(ax - bf2f(hx)), ly = f2bf(ay - bf2f(hy));
        *(unsigned int*)(Oh + (size_t)i * D + f) = (unsigned int)hx | ((unsigned int)hy << 16);
        *(unsigned int*)(Ol + (size_t)i * D + f) = (unsigned int)lx | ((unsigned int)ly << 16);
    } else {
        *(float2*)(Of + (size_t)i * D + f) = make_float2(ax, ay);
    }
}

// ---------------- launch ----------------

extern "C" void kernel_launch(void* const* d_in, const int* in_sizes, int n_in,
                              void* d_out, int out_size, void* d_ws, size_t ws_size,
                              hipStream_t stream) {
    const float* x  = (const float*)d_in[0];
    const int* edge = (const int*)d_in[1];
    const float* W0 = (const float*)d_in[2];
    const float* b0 = (const float*)d_in[3];
    const float* W1 = (const float*)d_in[4];
    const float* b1 = (const float*)d_in[5];
    const float* W2 = (const float*)d_in[6];
    const float* b2 = (const float*)d_in[7];
    const int* src = edge;
    const int* dst = edge + NE;
    float* out = (float*)d_out;

    char* ws = (char*)d_ws;
    size_t off = 0;
    auto alloc = [&](size_t bytes) {
        void* p = ws + off;
        off += (bytes + 255) & ~(size_t)255;
        return p;
    };
    int*   cnt    = (int*)alloc(NN * 4);
    int*   fill   = (int*)alloc(NN * 4);
    int*   rowptr = (int*)alloc((NN + 1) * 4);
    float* dinv   = (float*)alloc(NN * 4);
    int*   bsum   = (int*)alloc(256 * 4);
    int*   boff   = (int*)alloc(256 * 4);
    int*   col    = (int*)alloc((size_t)NE * 4);
    unsigned short* w0h = (unsigned short*)alloc(D * D * 2);
    unsigned short* w0l = (unsigned short*)alloc(D * D * 2);
    unsigned short* w1h = (unsigned short*)alloc(D * D * 2);
    unsigned short* w1l = (unsigned short*)alloc(D * D * 2);
    unsigned short* w2h = (unsigned short*)alloc(D * D * 2);
    unsigned short* w2l = (unsigned short*)alloc(D * D * 2);
    unsigned short* Xh = (unsigned short*)alloc((size_t)NPAD * D * 2);
    unsigned short* Xl = (unsigned short*)alloc((size_t)NPAD * D * 2);
    __half* T = (__half*)alloc((size_t)NPAD * D * 2);

    hipMemsetAsync(cnt, 0, NN * 4, stream);
    hipMemsetAsync(fill, 0, NN * 4, stream);

    k_degree<<<(NE + 255) / 256, 256, 0, stream>>>(dst, cnt);
    k_dinv<<<(NN + 255) / 256, 256, 0, stream>>>(cnt, dinv);
    k_scan_block<<<(NN + 255) / 256, 256, 0, stream>>>(cnt, rowptr, bsum);
    k_scan_top<<<1, 256, 0, stream>>>(bsum, boff);
    k_scan_add<<<(NN + 256) / 256, 256, 0, stream>>>(rowptr, boff);
    k_fill<<<(NE + 255) / 256, 256, 0, stream>>>(src, dst, rowptr, fill, col);

    k_convW<<<(D * D + 255) / 256, 256, 0, stream>>>(W0, w0h, w0l);
    k_convW<<<(D * D + 255) / 256, 256, 0, stream>>>(W1, w1h, w1l);
    k_convW<<<(D * D + 255) / 256, 256, 0, stream>>>(W2, w2h, w2l);
    k_convX<<<(NN * D / 4 + 255) / 256, 256, 0, stream>>>(x, Xh, Xl);

    const int ggrid = (NN + 63) / 64;   // 782
    const int agrid = (NN + 3) / 4;

    // layer 0
    k_gemm_mfma<<<ggrid, 256, 0, stream>>>(Xh, Xl, w0h, w0l, dinv, T);
    k_agg<<<agrid, 256, 0, stream>>>(T, rowptr, col, dinv, b0, Xh, Xl, out, 1);
    // layer 1
    k_gemm_mfma<<<ggrid, 256, 0, stream>>>(Xh, Xl, w1h, w1l, dinv, T);
    k_agg<<<agrid, 256, 0, stream>>>(T, rowptr, col, dinv, b1, Xh, Xl, out, 1);
    // layer 2 (no relu, fp32 out)
    k_gemm_mfma<<<ggrid, 256, 0, stream>>>(Xh, Xl, w2h, w2l, dinv, T);
    k_agg<<<agrid, 256, 0, stream>>>(T, rowptr, col, dinv, b2, Xh, Xl, out, 0);
}

// Round 5
// 244.036 us; speedup vs baseline: 2.1923x; 1.1587x over previous
//
#include <hip/hip_runtime.h>
#include <hip/hip_fp16.h>

#define NN 50000
#define NPAD 50048
#define NE 800000
#define D 128
#define BPAD 136

typedef __attribute__((ext_vector_type(8))) short bf16x8;
typedef __attribute__((ext_vector_type(4))) float f32x4;

__device__ inline unsigned short f2bf(float f) {
    unsigned int b = __float_as_uint(f);
    return (unsigned short)((b + 0x7FFFu + ((b >> 16) & 1u)) >> 16);
}
__device__ inline float bf2f(unsigned short u) {
    return __uint_as_float(((unsigned int)u) << 16);
}

// ---------------- CSR build ----------------

// degree + per-edge rank (order within dst bucket)
__global__ void k_degree(const int* __restrict__ dst, int* __restrict__ cnt,
                         int* __restrict__ rank) {
    int e = blockIdx.x * 256 + threadIdx.x;
    if (e < NE) {
        int d = dst[e];
        rank[e] = atomicAdd(&cnt[d], 1);
    }
}

__global__ void k_scan_block(const int* __restrict__ cnt, int* __restrict__ excl,
                             int* __restrict__ bsum) {
    __shared__ int sm[256];
    int t = threadIdx.x;
    int idx = blockIdx.x * 256 + t;
    int v = (idx < NN) ? cnt[idx] : 0;
    sm[t] = v;
    __syncthreads();
    for (int o = 1; o < 256; o <<= 1) {
        int u = (t >= o) ? sm[t - o] : 0;
        __syncthreads();
        sm[t] += u;
        __syncthreads();
    }
    if (idx < NN) excl[idx] = sm[t] - v;
    if (t == 255) bsum[blockIdx.x] = sm[255];
}

__global__ void k_scan_top(const int* __restrict__ bsum, int* __restrict__ boff) {
    __shared__ int sm[256];
    const int NB = (NN + 255) / 256;
    int t = threadIdx.x;
    int v = (t < NB) ? bsum[t] : 0;
    sm[t] = v;
    __syncthreads();
    for (int o = 1; o < 256; o <<= 1) {
        int u = (t >= o) ? sm[t - o] : 0;
        __syncthreads();
        sm[t] += u;
        __syncthreads();
    }
    if (t < NB) boff[t] = sm[t] - v;
}

// finalize rowptr + compute dinv (fused)
__global__ void k_scan_add(int* __restrict__ rowptr, const int* __restrict__ boff,
                           const int* __restrict__ cnt, float* __restrict__ dinv) {
    int idx = blockIdx.x * 256 + threadIdx.x;
    if (idx < NN) {
        rowptr[idx] += boff[idx >> 8];
        dinv[idx] = rsqrtf((float)(cnt[idx] + 1));
    } else if (idx == NN) {
        rowptr[NN] = NE;
    }
}

// atomic-free scatter
__global__ void k_fill(const int* __restrict__ src, const int* __restrict__ dst,
                       const int* __restrict__ rowptr, const int* __restrict__ rank,
                       int* __restrict__ col) {
    int e = blockIdx.x * 256 + threadIdx.x;
    if (e < NE) {
        int d = dst[e];
        int pos = rowptr[d] + rank[e];
        __builtin_nontemporal_store(src[e], &col[pos]);
    }
}

// ---------------- prep: W split-bf16, all 3 at once ----------------

__global__ void k_convW3(const float* __restrict__ W0, const float* __restrict__ W1,
                         const float* __restrict__ W2, unsigned short* __restrict__ Wh,
                         unsigned short* __restrict__ Wl) {
    int i = blockIdx.x * 256 + threadIdx.x;
    if (i >= 3 * D * D) return;
    int m = i / (D * D), r = i - m * (D * D);
    const float* W = (m == 0) ? W0 : ((m == 1) ? W1 : W2);
    int k = r >> 7, c = r & 127;
    float v = W[r];
    unsigned short h = f2bf(v);
    unsigned short l = f2bf(v - bf2f(h));
    Wh[(size_t)m * D * D + c * D + k] = h;
    Wl[(size_t)m * D * D + c * D + k] = l;
}

// ---------------- GEMM core (macro-free shared body via helpers) ----------

__device__ inline void gemm_store(f32x4 acc[2][4], const float* __restrict__ dinv,
                                  __half* __restrict__ C, int R0, int C0, int lr, int lg) {
    #pragma unroll
    for (int fr = 0; fr < 2; fr++) {
        int rb = R0 + fr * 16 + lg * 4;
        #pragma unroll
        for (int j = 0; j < 4; j++) {
            int r = rb + j;
            if (r < NN) {
                float s = dinv[r];
                #pragma unroll
                for (int fc = 0; fc < 4; fc++)
                    C[(size_t)r * D + C0 + fc * 16 + lr] =
                        __float2half_rn(acc[fr][fc][j] * s);
            }
        }
    }
}

// GEMM from split-bf16 activations (layers 1,2)
__global__ __launch_bounds__(256, 3) void k_gemm_mfma(
        const unsigned short* __restrict__ Ah, const unsigned short* __restrict__ Al,
        const unsigned short* __restrict__ BhT, const unsigned short* __restrict__ BlT,
        const float* __restrict__ dinv, __half* __restrict__ C) {
    __shared__ short Bs_h[D * BPAD];
    int t = threadIdx.x;
    {
        int c = t >> 1;
        int k0 = (t & 1) * 64;
        const unsigned short* gh = BhT + c * D + k0;
        short* dh = Bs_h + c * BPAD + k0;
        #pragma unroll
        for (int i = 0; i < 8; i++)
            *(int4*)(dh + i * 8) = *(const int4*)(gh + i * 8);
    }
    __syncthreads();

    int w = t >> 6, ln = t & 63;
    int wr = w >> 1, wc = w & 1;
    int R0 = blockIdx.x * 64 + wr * 32;
    int C0 = wc * 64;
    int lr = ln & 15, lg = ln >> 4;

    f32x4 acc[2][4];
    #pragma unroll
    for (int a = 0; a < 2; a++)
        #pragma unroll
        for (int b = 0; b < 4; b++)
            acc[a][b] = (f32x4){0.f, 0.f, 0.f, 0.f};

    const unsigned short* Abh = Ah + (size_t)(R0 + lr) * D + lg * 8;
    const unsigned short* Abl = Al + (size_t)(R0 + lr) * D + lg * 8;

    #pragma unroll
    for (int ks = 0; ks < 4; ks++) {
        int ko = ks * 32;
        bf16x8 fa_h[2], fa_l[2], fb_h[4], fb_l[4];
        #pragma unroll
        for (int fr = 0; fr < 2; fr++) {
            fa_h[fr] = *(const bf16x8*)(Abh + fr * 16 * D + ko);
            fa_l[fr] = *(const bf16x8*)(Abl + fr * 16 * D + ko);
        }
        #pragma unroll
        for (int fc = 0; fc < 4; fc++) {
            int ccol = C0 + fc * 16 + lr;
            fb_h[fc] = *(const bf16x8*)(Bs_h + ccol * BPAD + ko + lg * 8);
            fb_l[fc] = *(const bf16x8*)(BlT + (size_t)ccol * D + ko + lg * 8);
        }
        #pragma unroll
        for (int fr = 0; fr < 2; fr++) {
            #pragma unroll
            for (int fc = 0; fc < 4; fc++) {
                acc[fr][fc] = __builtin_amdgcn_mfma_f32_16x16x32_bf16(
                    fa_h[fr], fb_h[fc], acc[fr][fc], 0, 0, 0);
                acc[fr][fc] = __builtin_amdgcn_mfma_f32_16x16x32_bf16(
                    fa_l[fr], fb_h[fc], acc[fr][fc], 0, 0, 0);
                acc[fr][fc] = __builtin_amdgcn_mfma_f32_16x16x32_bf16(
                    fa_h[fr], fb_l[fc], acc[fr][fc], 0, 0, 0);
            }
        }
    }
    gemm_store(acc, dinv, C, R0, C0, lr, lg);
}

// GEMM layer 0: reads fp32 X, splits to bf16 in-register (convX fused)
__global__ __launch_bounds__(256, 2) void k_gemm_mfma_x(
        const float* __restrict__ X,
        const unsigned short* __restrict__ BhT, const unsigned short* __restrict__ BlT,
        const float* __restrict__ dinv, __half* __restrict__ C) {
    __shared__ short Bs_h[D * BPAD];
    int t = threadIdx.x;
    {
        int c = t >> 1;
        int k0 = (t & 1) * 64;
        const unsigned short* gh = BhT + c * D + k0;
        short* dh = Bs_h + c * BPAD + k0;
        #pragma unroll
        for (int i = 0; i < 8; i++)
            *(int4*)(dh + i * 8) = *(const int4*)(gh + i * 8);
    }
    __syncthreads();

    int w = t >> 6, ln = t & 63;
    int wr = w >> 1, wc = w & 1;
    int R0 = blockIdx.x * 64 + wr * 32;
    int C0 = wc * 64;
    int lr = ln & 15, lg = ln >> 4;

    f32x4 acc[2][4];
    #pragma unroll
    for (int a = 0; a < 2; a++)
        #pragma unroll
        for (int b = 0; b < 4; b++)
            acc[a][b] = (f32x4){0.f, 0.f, 0.f, 0.f};

    const float* Ab = X + (size_t)(R0 + lr) * D + lg * 8;

    #pragma unroll
    for (int ks = 0; ks < 4; ks++) {
        int ko = ks * 32;
        bf16x8 fa_h[2], fa_l[2], fb_h[4], fb_l[4];
        #pragma unroll
        for (int fr = 0; fr < 2; fr++) {
            float4 p0 = *(const float4*)(Ab + fr * 16 * D + ko);
            float4 p1 = *(const float4*)(Ab + fr * 16 * D + ko + 4);
            float vv[8] = {p0.x, p0.y, p0.z, p0.w, p1.x, p1.y, p1.z, p1.w};
            #pragma unroll
            for (int j = 0; j < 8; j++) {
                unsigned short h = f2bf(vv[j]);
                fa_h[fr][j] = (short)h;
                fa_l[fr][j] = (short)f2bf(vv[j] - bf2f(h));
            }
        }
        #pragma unroll
        for (int fc = 0; fc < 4; fc++) {
            int ccol = C0 + fc * 16 + lr;
            fb_h[fc] = *(const bf16x8*)(Bs_h + ccol * BPAD + ko + lg * 8);
            fb_l[fc] = *(const bf16x8*)(BlT + (size_t)ccol * D + ko + lg * 8);
        }
        #pragma unroll
        for (int fr = 0; fr < 2; fr++) {
            #pragma unroll
            for (int fc = 0; fc < 4; fc++) {
                acc[fr][fc] = __builtin_amdgcn_mfma_f32_16x16x32_bf16(
                    fa_h[fr], fb_h[fc], acc[fr][fc], 0, 0, 0);
                acc[fr][fc] = __builtin_amdgcn_mfma_f32_16x16x32_bf16(
                    fa_l[fr], fb_h[fc], acc[fr][fc], 0, 0, 0);
                acc[fr][fc] = __builtin_amdgcn_mfma_f32_16x16x32_bf16(
                    fa_h[fr], fb_l[fc], acc[fr][fc], 0, 0, 0);
            }
        }
    }
    gemm_store(acc, dinv, C, R0, C0, lr, lg);
}

// ---------------- Aggregation ----------------
// 32 lanes per node (2 nodes/wave), lane = 4 features via 8B gathers.
// T fp16 pre-scaled by dinv[row]. out[i] = dinv[i]*(sum_s T[s] + T[i]) + b.

__global__ __launch_bounds__(256) void k_agg(const __half* __restrict__ T,
                                             const int* __restrict__ rowptr,
                                             const int* __restrict__ col,
                                             const float* __restrict__ dinv,
                                             const float* __restrict__ bias,
                                             unsigned short* __restrict__ Oh,
                                             unsigned short* __restrict__ Ol,
                                             float* __restrict__ Of, int mode) {
    int i = blockIdx.x * 8 + (threadIdx.x >> 5);
    int sl = threadIdx.x & 31;
    int f = sl * 4;
    float di = dinv[i];
    float2 raw = *(const float2*)(T + (size_t)i * D + f);
    __half2 s0 = *(__half2*)&raw.x, s1 = *(__half2*)&raw.y;
    float2 g0 = __half22float2(s0), g1 = __half22float2(s1);
    float a0 = g0.x, a1 = g0.y, a2 = g1.x, a3 = g1.y;

    int e = rowptr[i], r1 = rowptr[i + 1];
    for (; e + 8 <= r1; e += 8) {
        float2 rv[8];
        #pragma unroll
        for (int u = 0; u < 8; u++) {
            int s = col[e + u];
            rv[u] = *(const float2*)(T + (size_t)s * D + f);
        }
        #pragma unroll
        for (int u = 0; u < 8; u++) {
            __half2 x0 = *(__half2*)&rv[u].x, x1 = *(__half2*)&rv[u].y;
            float2 q0 = __half22float2(x0), q1 = __half22float2(x1);
            a0 += q0.x; a1 += q0.y; a2 += q1.x; a3 += q1.y;
        }
    }
    for (; e + 4 <= r1; e += 4) {
        float2 rv[4];
        #pragma unroll
        for (int u = 0; u < 4; u++) {
            int s = col[e + u];
            rv[u] = *(const float2*)(T + (size_t)s * D + f);
        }
        #pragma unroll
        for (int u = 0; u < 4; u++) {
            __half2 x0 = *(__half2*)&rv[u].x, x1 = *(__half2*)&rv[u].y;
            float2 q0 = __half22float2(x0), q1 = __half22float2(x1);
            a0 += q0.x; a1 += q0.y; a2 += q1.x; a3 += q1.y;
        }
    }
    for (; e < r1; e++) {
        int s = col[e];
        float2 rv = *(const float2*)(T + (size_t)s * D + f);
        __half2 x0 = *(__half2*)&rv.x, x1 = *(__half2*)&rv.y;
        float2 q0 = __half22float2(x0), q1 = __half22float2(x1);
        a0 += q0.x; a1 += q0.y; a2 += q1.x; a3 += q1.y;
    }

    float4 bv = *(const float4*)(bias + f);
    a0 = a0 * di + bv.x;
    a1 = a1 * di + bv.y;
    a2 = a2 * di + bv.z;
    a3 = a3 * di + bv.w;
    if (mode) {
        a0 = fmaxf(a0, 0.f); a1 = fmaxf(a1, 0.f);
        a2 = fmaxf(a2, 0.f); a3 = fmaxf(a3, 0.f);
        unsigned short h0 = f2bf(a0), h1 = f2bf(a1), h2 = f2bf(a2), h3 = f2bf(a3);
        unsigned short l0 = f2bf(a0 - bf2f(h0)), l1 = f2bf(a1 - bf2f(h1));
        unsigned short l2 = f2bf(a2 - bf2f(h2)), l3 = f2bf(a3 - bf2f(h3));
        uint2 ph = make_uint2((unsigned)h0 | ((unsigned)h1 << 16),
                              (unsigned)h2 | ((unsigned)h3 << 16));
        uint2 pl = make_uint2((unsigned)l0 | ((unsigned)l1 << 16),
                              (unsigned)l2 | ((unsigned)l3 << 16));
        *(uint2*)(Oh + (size_t)i * D + f) = ph;
        *(uint2*)(Ol + (size_t)i * D + f) = pl;
    } else {
        *(float4*)(Of + (size_t)i * D + f) = make_float4(a0, a1, a2, a3);
    }
}

// ---------------- launch ----------------

extern "C" void kernel_launch(void* const* d_in, const int* in_sizes, int n_in,
                              void* d_out, int out_size, void* d_ws, size_t ws_size,
                              hipStream_t stream) {
    const float* x  = (const float*)d_in[0];
    const int* edge = (const int*)d_in[1];
    const float* W0 = (const float*)d_in[2];
    const float* b0 = (const float*)d_in[3];
    const float* W1 = (const float*)d_in[4];
    const float* b1 = (const float*)d_in[5];
    const float* W2 = (const float*)d_in[6];
    const float* b2 = (const float*)d_in[7];
    const int* src = edge;
    const int* dst = edge + NE;
    float* out = (float*)d_out;

    char* ws = (char*)d_ws;
    size_t off = 0;
    auto alloc = [&](size_t bytes) {
        void* p = ws + off;
        off += (bytes + 255) & ~(size_t)255;
        return p;
    };
    int*   cnt    = (int*)alloc(NN * 4);
    int*   rowptr = (int*)alloc((NN + 1) * 4);
    float* dinv   = (float*)alloc(NN * 4);
    int*   bsum   = (int*)alloc(256 * 4);
    int*   boff   = (int*)alloc(256 * 4);
    int*   rank   = (int*)alloc((size_t)NE * 4);
    int*   col    = (int*)alloc((size_t)NE * 4);
    unsigned short* Wh = (unsigned short*)alloc(3 * D * D * 2);
    unsigned short* Wl = (unsigned short*)alloc(3 * D * D * 2);
    unsigned short* Xh = (unsigned short*)alloc((size_t)NPAD * D * 2);
    unsigned short* Xl = (unsigned short*)alloc((size_t)NPAD * D * 2);
    __half* T = (__half*)alloc((size_t)NPAD * D * 2);

    hipMemsetAsync(cnt, 0, NN * 4, stream);

    k_degree<<<(NE + 255) / 256, 256, 0, stream>>>(dst, cnt, rank);
    k_scan_block<<<(NN + 255) / 256, 256, 0, stream>>>(cnt, rowptr, bsum);
    k_scan_top<<<1, 256, 0, stream>>>(bsum, boff);
    k_scan_add<<<(NN + 256) / 256, 256, 0, stream>>>(rowptr, boff, cnt, dinv);
    k_fill<<<(NE + 255) / 256, 256, 0, stream>>>(src, dst, rowptr, rank, col);
    k_convW3<<<(3 * D * D + 255) / 256, 256, 0, stream>>>(W0, W1, W2, Wh, Wl);

    const int ggrid = (NN + 63) / 64;   // 782
    const int agrid = NN / 8;           // 6250

    // layer 0 (conv fused into GEMM)
    k_gemm_mfma_x<<<ggrid, 256, 0, stream>>>(x, Wh, Wl, dinv, T);
    k_agg<<<agrid, 256, 0, stream>>>(T, rowptr, col, dinv, b0, Xh, Xl, out, 1);
    // layer 1
    k_gemm_mfma<<<ggrid, 256, 0, stream>>>(Xh, Xl, Wh + D * D, Wl + D * D, dinv, T);
    k_agg<<<agrid, 256, 0, stream>>>(T, rowptr, col, dinv, b1, Xh, Xl, out, 1);
    // layer 2 (no relu, fp32 out)
    k_gemm_mfma<<<ggrid, 256, 0, stream>>>(Xh, Xl, Wh + 2 * D * D, Wl + 2 * D * D, dinv, T);
    k_agg<<<agrid, 256, 0, stream>>>(T, rowptr, col, dinv, b2, Xh, Xl, out, 0);
}